// Round 3
// baseline (162365.161 us; speedup 1.0000x reference)
//
#include <hip/hip_runtime.h>
#include <math.h>

// ESN reservoir recurrence, persistent-kernel formulation.
// x_{s+1} = 0.3*x_s + 0.7*tanh(0.9*W @ x_s + win0 * u[s])
// out[d][s-1001] = x_{s+1}[d] for s >= 1001   (out is 900 x 29999, row-major)
//
// R2: W register-resident (float4 wreg[4][4]/wave), per-wave flag poll fused
// with x staging, output staged in LDS ring + flushed off-critical-path.

#define DIM        900
#define T_TOTAL    31000
#define DISCARD_P1 1001
#define OUT_T      29999
#define NBLK       60
#define ROWS_PB    15
#define NTHREADS   256
#define SR         0.9f
#define LEAKY      0.7f
#define RING_W     32            // steps buffered per output flush

// Workspace layout (floats):
//   [0..1023]     xbuf parity 0  (NBLK blocks x 16-float padded lines; 960 used)
//   [1024..2047]  xbuf parity 1
//   [2048..3967]  flags: one u32 per block, 32-float (128 B) stride
#define XBUF_F      1024
#define FLAG_OFF    2048
#define FLAG_STRIDE 32
#define WS_INIT_N   4096

__global__ void esn_init_ws(float* ws) {
    int i = threadIdx.x + blockIdx.x * blockDim.x;
    if (i < WS_INIT_N) ws[i] = 0.0f;
}

__launch_bounds__(NTHREADS, 1)
__global__ void esn_persistent(const float* __restrict__ W,
                               const float* __restrict__ W_in,
                               const float* __restrict__ u,
                               float* __restrict__ out,
                               float* xbuf,                  // 2 * XBUF_F floats
                               unsigned int* flags)          // NBLK, FLAG_STRIDE apart
{
    __shared__ float x_lds[1024];                 // cols 0..899 live, 900..1023 = 0
    __shared__ float ring[ROWS_PB][RING_W + 1];   // +1 pad breaks bank aliasing

    const int tid   = threadIdx.x;
    const int blk   = blockIdx.x;
    const int row0  = blk * ROWS_PB;
    const int wave  = tid >> 6;
    const int lane  = tid & 63;
    const int rbase = wave * 4;                   // this wave's rows rbase..rbase+3

    // Zero x_lds (pad region stays zero forever; cols <900 rewritten per step).
    for (int i = tid; i < 1024; i += NTHREADS) x_lds[i] = 0.0f;

    // Stage 0.9*W into registers: wreg[r][k] covers row (rbase+r),
    // columns 4*lane + 256*k .. +3. Out-of-range -> 0 (so pad x cols are inert).
    float4 wreg[4][4];
    #pragma unroll
    for (int r = 0; r < 4; ++r) {
        const int row = rbase + r;
        #pragma unroll
        for (int k = 0; k < 4; ++k) {
            const int c = 4 * lane + 256 * k;
            float4 v = make_float4(0.f, 0.f, 0.f, 0.f);
            if (row < ROWS_PB && c + 3 < DIM) {
                const float4 w4 = *reinterpret_cast<const float4*>(
                    W + (size_t)(row0 + row) * DIM + c);
                v = make_float4(SR * w4.x, SR * w4.y, SR * w4.z, SR * w4.w);
            }
            wreg[r][k] = v;
        }
    }
    float win0r = 0.0f;
    if (lane < 4 && rbase + lane < ROWS_PB)
        win0r = W_in[(size_t)(row0 + rbase + lane) * DIM];   // column 0

    __syncthreads();   // x_lds zeros visible

    for (int s = 0; s < T_TOTAL; ++s) {
        // ---- per-wave barrier: wave w waits on the 15 source blocks of its
        //      x-quarter (lanes 0..14 spin; wave reconverges when all ready) ----
        if (s > 0) {
            if (lane < ROWS_PB) {
                const unsigned int tgt = (unsigned int)s;
                while (__hip_atomic_load(flags + (wave * 15 + lane) * FLAG_STRIDE,
                                         __ATOMIC_ACQUIRE,
                                         __HIP_MEMORY_SCOPE_AGENT) < tgt) { }
            }
        }

        // ---- stage this wave's quarter of x (blocks 15w..15w+14, 240 floats) ----
        const float* xin = xbuf + (size_t)(s & 1) * XBUF_F;
        if (lane < 60) {
            const int bl = lane >> 2;            // local source block 0..14
            const int j  = (lane & 3) * 4;       // 0,4,8,12 within 15-value line
            const float* src = xin + (size_t)(wave * 15 + bl) * 16 + j;
            const float v0 = __hip_atomic_load(src + 0, __ATOMIC_RELAXED,
                                               __HIP_MEMORY_SCOPE_AGENT);
            const float v1 = __hip_atomic_load(src + 1, __ATOMIC_RELAXED,
                                               __HIP_MEMORY_SCOPE_AGENT);
            const float v2 = __hip_atomic_load(src + 2, __ATOMIC_RELAXED,
                                               __HIP_MEMORY_SCOPE_AGENT);
            const float v3 = __hip_atomic_load(src + 3, __ATOMIC_RELAXED,
                                               __HIP_MEMORY_SCOPE_AGENT);
            const int base = (wave * 15 + bl) * 15 + j;
            x_lds[base + 0] = v0;
            x_lds[base + 1] = v1;
            x_lds[base + 2] = v2;
            if (j != 12) x_lds[base + 3] = v3;   // j==12 line carries only 3 live
        }
        const float ut = u[s];
        __syncthreads();

        // ---- matvec: 4 rows/wave from registers, x via ds_read_b128 ----
        float a0 = 0.f, a1 = 0.f, a2 = 0.f, a3 = 0.f;
        #pragma unroll
        for (int k = 0; k < 4; ++k) {
            const float4 xv = *reinterpret_cast<const float4*>(&x_lds[4 * lane + 256 * k]);
            a0 += wreg[0][k].x * xv.x + wreg[0][k].y * xv.y
                + wreg[0][k].z * xv.z + wreg[0][k].w * xv.w;
            a1 += wreg[1][k].x * xv.x + wreg[1][k].y * xv.y
                + wreg[1][k].z * xv.z + wreg[1][k].w * xv.w;
            a2 += wreg[2][k].x * xv.x + wreg[2][k].y * xv.y
                + wreg[2][k].z * xv.z + wreg[2][k].w * xv.w;
            a3 += wreg[3][k].x * xv.x + wreg[3][k].y * xv.y
                + wreg[3][k].z * xv.z + wreg[3][k].w * xv.w;
        }
        #pragma unroll
        for (int off = 1; off < 64; off <<= 1) {
            a0 += __shfl_xor(a0, off, 64);
            a1 += __shfl_xor(a1, off, 64);
            a2 += __shfl_xor(a2, off, 64);
            a3 += __shfl_xor(a3, off, 64);
        }

        // ---- epilogue: lanes 0..3 finish rows rbase..rbase+3 ----
        if (lane < 4 && rbase + lane < ROWS_PB) {
            const float acc = (lane == 0) ? a0 : (lane == 1) ? a1
                            : (lane == 2) ? a2 : a3;
            const int grow = row0 + rbase + lane;
            float z = acc + win0r * ut;
            z = fminf(fmaxf(z, -9.0f), 9.0f);
            const float e  = __expf(2.0f * z);
            const float th = (e - 1.0f) / (e + 1.0f);
            const float xn = (1.0f - LEAKY) * x_lds[grow] + LEAKY * th;
            float* xout = xbuf + (size_t)((s + 1) & 1) * XBUF_F;
            __hip_atomic_store(xout + (size_t)blk * 16 + rbase + lane, xn,
                               __ATOMIC_RELAXED, __HIP_MEMORY_SCOPE_AGENT);
            if (s >= DISCARD_P1)
                ring[rbase + lane][(s - DISCARD_P1) & (RING_W - 1)] = xn;
        }

        // All waves' xout stores drain (vmcnt(0) before s_barrier), then signal.
        __syncthreads();
        if (tid == 0)
            __hip_atomic_store(flags + (size_t)blk * FLAG_STRIDE,
                               (unsigned int)(s + 1),
                               __ATOMIC_RELEASE, __HIP_MEMORY_SCOPE_AGENT);

        // ---- output flush: AFTER the release -> off the inter-block path ----
        if (s >= DISCARD_P1) {
            const int c = s - DISCARD_P1;
            const bool last = (s == T_TOTAL - 1);
            if ((c & (RING_W - 1)) == (RING_W - 1) || last) {
                const int len = (c & (RING_W - 1)) + 1;
                const int c0  = c - len + 1;
                if (len == RING_W) {
                    for (int i = tid; i < ROWS_PB * RING_W; i += NTHREADS) {
                        const int row = i >> 5, col = i & (RING_W - 1);
                        out[(size_t)(row0 + row) * OUT_T + c0 + col] = ring[row][col];
                    }
                } else {
                    for (int i = tid; i < ROWS_PB * len; i += NTHREADS) {
                        const int row = i / len, col = i % len;
                        out[(size_t)(row0 + row) * OUT_T + c0 + col] = ring[row][col];
                    }
                }
            }
        }
        // Next step's pre-compute __syncthreads orders flush LDS-reads vs. the
        // following ring writes; ring slot 0 is only rewritten after it.
    }
}

extern "C" void kernel_launch(void* const* d_in, const int* in_sizes, int n_in,
                              void* d_out, int out_size, void* d_ws, size_t ws_size,
                              hipStream_t stream) {
    const float* W    = (const float*)d_in[0];
    const float* W_in = (const float*)d_in[1];
    const float* u    = (const float*)d_in[2];
    float* out = (float*)d_out;
    float* ws  = (float*)d_ws;

    esn_init_ws<<<WS_INIT_N / 256, 256, 0, stream>>>(ws);
    esn_persistent<<<NBLK, NTHREADS, 0, stream>>>(
        W, W_in, u, out, ws, (unsigned int*)(ws + FLAG_OFF));
}

// Round 4
// 57666.248 us; speedup vs baseline: 2.8156x; 2.8156x over previous
//
#include <hip/hip_runtime.h>
#include <math.h>

// ESN reservoir recurrence, persistent-kernel, one-line mailbox protocol.
// x_{s+1} = 0.3*x_s + 0.7*tanh(0.9*W @ x_s + win0 * u[s])
// out[d][s-1001] = x_{s+1}[d] for s >= 1001   (out is 900 x 29999, row-major)
//
// Each block owns 15 rows. Per step it publishes ONE 64B line:
// 15 x-values + float tag (=state index), stored with a single
// global_store_dwordx4 sc0 sc1 from 4 lanes -> data+tag visible together.
// Consumers spin-load the source lines directly (tag check == flag+data in
// one LLC round trip). No atomics, no acquire/release, no store drain.

#define DIM        900
#define T_TOTAL    31000
#define DISCARD_P1 1001
#define OUT_T      29999
#define NBLK       60
#define ROWS_PB    15
#define NTHREADS   256
#define SR         0.9f
#define LEAKY      0.7f
#define RING_W     64

// Workspace (floats): [0..1023] parity-0 lines, [1024..2047] parity-1 lines.
// Line b = 16 floats: x[15 rows] + tag. Zero-init == state 0 with tag 0.0f.
#define XBUF_F    1024
#define WS_INIT_N 2048

typedef float vfloat4 __attribute__((ext_vector_type(4)));

__global__ void esn_init_ws(float* ws) {
    int i = threadIdx.x + blockIdx.x * blockDim.x;
    if (i < WS_INIT_N) ws[i] = 0.0f;
}

__device__ __forceinline__ vfloat4 load_line16(const float* p) {
    vfloat4 v;
    asm volatile("global_load_dwordx4 %0, %1, off sc0 sc1\n\t"
                 "s_waitcnt vmcnt(0)"
                 : "=v"(v) : "v"(p) : "memory");
    return v;
}
__device__ __forceinline__ void store_line16(float* p, vfloat4 v) {
    asm volatile("global_store_dwordx4 %0, %1, off sc0 sc1"
                 :: "v"(p), "v"(v) : "memory");
}

__launch_bounds__(NTHREADS, 1)
__global__ void esn_persistent(const float* __restrict__ W,
                               const float* __restrict__ W_in,
                               const float* __restrict__ u,
                               float* __restrict__ out,
                               float* xbuf)
{
    __shared__ float x_lds[1024];                 // padded x: 60 lines x 16
    __shared__ float ring[ROWS_PB][RING_W + 1];   // output staging
    __shared__ float res[16];                     // this block's next line

    const int tid   = threadIdx.x;
    const int blk   = blockIdx.x;
    const int row0  = blk * ROWS_PB;
    const int wave  = tid >> 6;
    const int lane  = tid & 63;
    const int rbase = wave * 4;                   // rows rbase..rbase+3 (15=pad)

    for (int i = tid; i < 1024; i += NTHREADS) x_lds[i] = 0.0f;

    // W in registers over the PADDED 960-col layout: padded index p ->
    // source p>>4, offset p&15; offset 15 is the tag column -> W := 0.
    vfloat4 wreg[4][4];
    #pragma unroll
    for (int r = 0; r < 4; ++r) {
        const int row = rbase + r;
        #pragma unroll
        for (int k = 0; k < 4; ++k) {
            const int p = 4 * lane + 256 * k;
            vfloat4 v = (vfloat4)0.0f;
            if (row < ROWS_PB) {
                #pragma unroll
                for (int j = 0; j < 4; ++j) {
                    const int pp  = p + j;
                    const int off = pp & 15;
                    if (pp < 960 && off < 15) {
                        const int col = (pp >> 4) * 15 + off;
                        v[j] = SR * W[(size_t)(row0 + row) * DIM + col];
                    }
                }
            }
            wreg[r][k] = v;
        }
    }
    float win0r = 0.0f;
    if (lane < 4 && rbase + lane < ROWS_PB)
        win0r = W_in[(size_t)(row0 + rbase + lane) * DIM];   // column 0

    // Poll assignment: wave w covers source lines 15w..15w+14, 4 lanes/line.
    const int  sidx    = wave * 15 + (lane >> 2);   // valid for lane < 60
    const int  chunk   = lane & 3;
    const bool taglane = (lane < 60) && (chunk == 3);

    __syncthreads();   // x_lds zeros visible

    for (int s = 0; s < T_TOTAL; ++s) {
        const float ut  = u[s];
        const float tag = (float)s;
        const float* xin = xbuf + (size_t)(s & 1) * XBUF_F;

        // ---- combined spin + x load: one RT delivers tag AND data ----
        if (lane < 60) {
            const float* src = xin + sidx * 16 + chunk * 4;
            vfloat4 v;
            for (;;) {
                v = load_line16(src);
                const bool ok = !taglane || (v.w == tag);
                if (__all(ok)) break;
            }
            *reinterpret_cast<vfloat4*>(&x_lds[sidx * 16 + chunk * 4]) = v;
        }
        __syncthreads();   // S1: full padded x staged

        // ---- matvec: 4 rows/wave, W from registers, x via ds_read_b128 ----
        float a0 = 0.f, a1 = 0.f, a2 = 0.f, a3 = 0.f;
        #pragma unroll
        for (int k = 0; k < 4; ++k) {
            const vfloat4 xv =
                *reinterpret_cast<const vfloat4*>(&x_lds[4 * lane + 256 * k]);
            a0 += wreg[0][k].x * xv.x + wreg[0][k].y * xv.y
                + wreg[0][k].z * xv.z + wreg[0][k].w * xv.w;
            a1 += wreg[1][k].x * xv.x + wreg[1][k].y * xv.y
                + wreg[1][k].z * xv.z + wreg[1][k].w * xv.w;
            a2 += wreg[2][k].x * xv.x + wreg[2][k].y * xv.y
                + wreg[2][k].z * xv.z + wreg[2][k].w * xv.w;
            a3 += wreg[3][k].x * xv.x + wreg[3][k].y * xv.y
                + wreg[3][k].z * xv.z + wreg[3][k].w * xv.w;
        }
        #pragma unroll
        for (int off = 1; off < 64; off <<= 1) {
            a0 += __shfl_xor(a0, off, 64);
            a1 += __shfl_xor(a1, off, 64);
            a2 += __shfl_xor(a2, off, 64);
            a3 += __shfl_xor(a3, off, 64);
        }

        // ---- epilogue: lanes 0..3 per wave finish one row each ----
        if (lane < 4) {
            const int r = rbase + lane;                 // 0..15
            if (r < ROWS_PB) {
                const float acc = (lane == 0) ? a0 : (lane == 1) ? a1
                                : (lane == 2) ? a2 : a3;
                float z = acc + win0r * ut;
                z = fminf(fmaxf(z, -9.0f), 9.0f);
                const float e  = __expf(2.0f * z);
                const float th = (e - 1.0f) / (e + 1.0f);
                const float xn = (1.0f - LEAKY) * x_lds[blk * 16 + r]
                               + LEAKY * th;
                res[r] = xn;
                if (s >= DISCARD_P1)
                    ring[r][(s - DISCARD_P1) & (RING_W - 1)] = xn;
            } else {
                res[15] = (float)(s + 1);               // tag for new state
            }
        }
        __syncthreads();   // S2: res complete

        // ---- publish: ONE 64B store carries 15 values + tag ----
        if (tid < 4) {
            const vfloat4 rv =
                *reinterpret_cast<const vfloat4*>(&res[4 * tid]);
            store_line16(xbuf + (size_t)((s + 1) & 1) * XBUF_F
                              + (size_t)blk * 16 + 4 * tid, rv);
        }

        // ---- output flush: after publish -> off the inter-block path ----
        if (s >= DISCARD_P1) {
            const int  c    = s - DISCARD_P1;
            const bool last = (s == T_TOTAL - 1);
            if ((c & (RING_W - 1)) == (RING_W - 1) || last) {
                const int len = (c & (RING_W - 1)) + 1;
                const int c0  = c - len + 1;
                if (len == RING_W) {
                    for (int i = tid; i < ROWS_PB * RING_W; i += NTHREADS) {
                        const int row = i >> 6, col = i & (RING_W - 1);
                        out[(size_t)(row0 + row) * OUT_T + c0 + col] =
                            ring[row][col];
                    }
                } else {
                    for (int i = tid; i < ROWS_PB * len; i += NTHREADS) {
                        const int row = i / len, col = i % len;
                        out[(size_t)(row0 + row) * OUT_T + c0 + col] =
                            ring[row][col];
                    }
                }
            }
        }
        // Next step's S1 orders this flush's ring reads vs. future ring writes.
    }
}

extern "C" void kernel_launch(void* const* d_in, const int* in_sizes, int n_in,
                              void* d_out, int out_size, void* d_ws, size_t ws_size,
                              hipStream_t stream) {
    const float* W    = (const float*)d_in[0];
    const float* W_in = (const float*)d_in[1];
    const float* u    = (const float*)d_in[2];
    float* out = (float*)d_out;
    float* ws  = (float*)d_ws;

    esn_init_ws<<<WS_INIT_N / 256, 256, 0, stream>>>(ws);
    esn_persistent<<<NBLK, NTHREADS, 0, stream>>>(W, W_in, u, out, ws);
}